// Round 1
// baseline (2231.606 us; speedup 1.0000x reference)
//
#include <hip/hip_runtime.h>
#include <hip/hip_bf16.h>
#include <stdint.h>

// Problem constants (B=8, S=4096 -> N rows; C = M = 2048)
#define NROWS 32768
#define KDIM  2048   // inner dim of both GEMMs
#define MDIM  2048   // output cols of both GEMMs

typedef __attribute__((ext_vector_type(8))) __bf16 bf16x8;
typedef __attribute__((ext_vector_type(4))) __bf16 bf16x4;
typedef __attribute__((ext_vector_type(4))) float  f32x4;

// ---------------------------------------------------------------------------
// async global->LDS, 16B per lane, wave-uniform LDS base + lane*16
// ---------------------------------------------------------------------------
__device__ __forceinline__ void gload16(const __bf16* g, __bf16* l) {
    __builtin_amdgcn_global_load_lds(
        (__attribute__((address_space(1))) void*)(g),
        (__attribute__((address_space(3))) void*)(l), 16, 0, 0);
}

// ---------------------------------------------------------------------------
// Weight transpose + bf16 hi/lo split:  W[K][M] fp32 -> Wt_hi/Wt_lo [M][K] bf16
// ---------------------------------------------------------------------------
__global__ __launch_bounds__(256) void wsplit(const float* __restrict__ W,
                                              __bf16* __restrict__ th,
                                              __bf16* __restrict__ tl) {
    __shared__ float tile[32][33];
    const int bx = blockIdx.x & 63;   // m-tile
    const int by = blockIdx.x >> 6;   // k-tile
    const int tx = threadIdx.x & 31;
    const int ty = threadIdx.x >> 5;  // 0..7
#pragma unroll
    for (int i = 0; i < 32; i += 8)
        tile[ty + i][tx] = W[(size_t)(by * 32 + ty + i) * MDIM + bx * 32 + tx];
    __syncthreads();
#pragma unroll
    for (int i = 0; i < 32; i += 8) {
        const int m = bx * 32 + ty + i;
        const int k = by * 32 + tx;
        const float v = tile[tx][ty + i];
        const __bf16 hb = (__bf16)v;
        const __bf16 lb = (__bf16)(v - (float)hb);
        th[(size_t)m * KDIM + k] = hb;
        tl[(size_t)m * KDIM + k] = lb;
    }
}

// ---------------------------------------------------------------------------
// Fused LayerNorm + SiLU + bf16 hi/lo split. One block per row (C=2048).
// ---------------------------------------------------------------------------
__global__ __launch_bounds__(256) void ln_silu_split(const float* __restrict__ in,
                                                     const float* __restrict__ g,
                                                     const float* __restrict__ beta,
                                                     __bf16* __restrict__ hi,
                                                     __bf16* __restrict__ lo) {
    const int row  = blockIdx.x;
    const int tid  = threadIdx.x;
    const int lane = tid & 63;
    const int wv   = tid >> 6;
    const float* rp = in + (size_t)row * KDIM;

    const float4 v0 = ((const float4*)rp)[tid];         // cols 4t .. 4t+3
    const float4 v1 = ((const float4*)rp)[tid + 256];   // cols 1024+4t ..

    float s = v0.x + v0.y + v0.z + v0.w + v1.x + v1.y + v1.z + v1.w;
    float q = v0.x * v0.x + v0.y * v0.y + v0.z * v0.z + v0.w * v0.w +
              v1.x * v1.x + v1.y * v1.y + v1.z * v1.z + v1.w * v1.w;

#pragma unroll
    for (int off = 32; off > 0; off >>= 1) {
        s += __shfl_xor(s, off, 64);
        q += __shfl_xor(q, off, 64);
    }
    __shared__ float red[8];
    if (lane == 0) { red[wv] = s; red[4 + wv] = q; }
    __syncthreads();
    s = red[0] + red[1] + red[2] + red[3];
    q = red[4] + red[5] + red[6] + red[7];

    const float mu   = s * (1.0f / KDIM);
    const float var  = q * (1.0f / KDIM) - mu * mu;
    const float rstd = rsqrtf(var + 1e-6f);

    auto emit = [&](float4 v, int c0) {
        bf16x4 h4, l4;
        const float xs[4] = {v.x, v.y, v.z, v.w};
#pragma unroll
        for (int j = 0; j < 4; j++) {
            const int c = c0 + j;
            const float t  = (xs[j] - mu) * rstd * g[c] + beta[c];
            const float sv = t / (1.0f + __expf(-t));
            const __bf16 hb = (__bf16)sv;
            const __bf16 lb = (__bf16)(sv - (float)hb);
            h4[j] = hb; l4[j] = lb;
        }
        *(bf16x4*)(hi + (size_t)row * KDIM + c0) = h4;
        *(bf16x4*)(lo + (size_t)row * KDIM + c0) = l4;
    };
    emit(v0, tid * 4);
    emit(v1, 1024 + tid * 4);
}

// ---------------------------------------------------------------------------
// Split-bf16 GEMM:  out[N][M] = A[N][K] * Bt[M][K]^T (+bias) (+residual)
// A, Bt given as bf16 hi/lo planes; acc += hi*hi + hi*lo + lo*hi  (fp32)
// 128x128 tile, BK=32, 256 threads (4 waves, each 64x64), 16x16x32 MFMA.
// ---------------------------------------------------------------------------
__global__ __launch_bounds__(256, 2) void gemm_split(
        const __bf16* __restrict__ Ah, const __bf16* __restrict__ Al,
        const __bf16* __restrict__ Bh, const __bf16* __restrict__ Bl,
        const float* __restrict__ bias, const float* __restrict__ res,
        float* __restrict__ out) {
    __shared__ __align__(16) __bf16 sAh[128 * 32];
    __shared__ __align__(16) __bf16 sAl[128 * 32];
    __shared__ __align__(16) __bf16 sBh[128 * 32];
    __shared__ __align__(16) __bf16 sBl[128 * 32];

    const int tid  = threadIdx.x;
    const int lane = tid & 63;
    const int wv   = tid >> 6;     // 0..3
    const int wr   = wv >> 1;      // wave row (0..1)
    const int wc   = wv & 1;       // wave col (0..1)
    const int ml   = lane & 15;
    const int qk   = lane >> 4;    // 0..3

    const int bx = blockIdx.x;
    const int m0 = (bx >> 4) * 128;   // row-tile base (N/128 = 256 tiles)
    const int n0 = (bx & 15) * 128;   // col-tile base (M/128 = 16 tiles)

    // staging geometry: wave wv covers LDS element blocks (wv*2+q)*512, q=0..1
    const int ch   = wv * 2;
    const int srow = lane >> 2;          // 0..15
    const int skof = (lane & 3) * 8;     // 0,8,16,24

    f32x4 acc[4][4] = {};

    for (int kb = 0; kb < KDIM; kb += 32) {
#pragma unroll
        for (int qq = 0; qq < 2; qq++) {
            const int r    = (ch + qq) * 16 + srow;
            const int lofs = (ch + qq) * 512;
            const size_t ga = (size_t)(m0 + r) * KDIM + kb + skof;
            const size_t gb = (size_t)(n0 + r) * KDIM + kb + skof;
            gload16(Ah + ga, sAh + lofs);
            gload16(Al + ga, sAl + lofs);
            gload16(Bh + gb, sBh + lofs);
            gload16(Bl + gb, sBl + lofs);
        }
        __syncthreads();

        bf16x8 ah[4], al[4];
#pragma unroll
        for (int mi = 0; mi < 4; mi++) {
            const int ao = (wr * 64 + mi * 16 + ml) * 32 + qk * 8;
            ah[mi] = *(const bf16x8*)&sAh[ao];
            al[mi] = *(const bf16x8*)&sAl[ao];
        }
#pragma unroll
        for (int ni = 0; ni < 4; ni++) {
            const int bo = (wc * 64 + ni * 16 + ml) * 32 + qk * 8;
            const bf16x8 bh = *(const bf16x8*)&sBh[bo];
            const bf16x8 bl = *(const bf16x8*)&sBl[bo];
#pragma unroll
            for (int mi = 0; mi < 4; mi++) {
                acc[mi][ni] = __builtin_amdgcn_mfma_f32_16x16x32_bf16(ah[mi], bh, acc[mi][ni], 0, 0, 0);
                acc[mi][ni] = __builtin_amdgcn_mfma_f32_16x16x32_bf16(ah[mi], bl, acc[mi][ni], 0, 0, 0);
                acc[mi][ni] = __builtin_amdgcn_mfma_f32_16x16x32_bf16(al[mi], bh, acc[mi][ni], 0, 0, 0);
            }
        }
        __syncthreads();
    }

    // epilogue: C/D layout col = lane&15, row = qk*4 + reg
#pragma unroll
    for (int mi = 0; mi < 4; mi++) {
        const int gm = m0 + wr * 64 + mi * 16 + qk * 4;
#pragma unroll
        for (int ni = 0; ni < 4; ni++) {
            const int gn = n0 + wc * 64 + ni * 16 + ml;
            const float bv = bias[gn];
#pragma unroll
            for (int r = 0; r < 4; r++) {
                const size_t idx = (size_t)(gm + r) * MDIM + gn;
                float v = acc[mi][ni][r] + bv;
                if (res) v += res[idx];
                out[idx] = v;
            }
        }
    }
}

// ---------------------------------------------------------------------------
// Orchestration
//   ws layout (bytes):
//     [0,       128MB)  Ah  (activation hi plane, N*K bf16)
//     [128MB,   256MB)  Al  (activation lo plane)
//     [256MB,   264MB)  B1h   [264MB, 272MB) B1l
//     [272MB,   280MB)  B2h   [280MB, 288MB) B2l
//   y1 (GEMM1 output, fp32 N*M) lives in d_out until overwritten by GEMM2.
// ---------------------------------------------------------------------------
extern "C" void kernel_launch(void* const* d_in, const int* in_sizes, int n_in,
                              void* d_out, int out_size, void* d_ws, size_t ws_size,
                              hipStream_t stream) {
    const float* x   = (const float*)d_in[0];
    const float* w1  = (const float*)d_in[1];
    const float* b1  = (const float*)d_in[2];
    const float* w2  = (const float*)d_in[3];
    const float* b2  = (const float*)d_in[4];
    const float* g1  = (const float*)d_in[5];
    const float* be1 = (const float*)d_in[6];
    const float* g2  = (const float*)d_in[7];
    const float* be2 = (const float*)d_in[8];
    float* out = (float*)d_out;

    char* ws = (char*)d_ws;
    const size_t PLANE = (size_t)NROWS * KDIM * 2;   // 128 MiB
    const size_t WPL   = (size_t)KDIM * MDIM * 2;    // 8 MiB
    __bf16* Ah  = (__bf16*)(ws);
    __bf16* Al  = (__bf16*)(ws + PLANE);
    __bf16* B1h = (__bf16*)(ws + 2 * PLANE);
    __bf16* B1l = (__bf16*)(ws + 2 * PLANE + WPL);
    __bf16* B2h = (__bf16*)(ws + 2 * PLANE + 2 * WPL);
    __bf16* B2l = (__bf16*)(ws + 2 * PLANE + 3 * WPL);

    wsplit<<<4096, 256, 0, stream>>>(w1, B1h, B1l);
    wsplit<<<4096, 256, 0, stream>>>(w2, B2h, B2l);

    ln_silu_split<<<NROWS, 256, 0, stream>>>(x, g1, be1, Ah, Al);
    gemm_split<<<(NROWS / 128) * (MDIM / 128), 256, 0, stream>>>(
        Ah, Al, B1h, B1l, b1, nullptr, out);

    ln_silu_split<<<NROWS, 256, 0, stream>>>(out, g2, be2, Ah, Al);
    gemm_split<<<(NROWS / 128) * (MDIM / 128), 256, 0, stream>>>(
        Ah, Al, B2h, B2l, b2, x, out);
}

// Round 2
// 1714.169 us; speedup vs baseline: 1.3019x; 1.3019x over previous
//
#include <hip/hip_runtime.h>
#include <hip/hip_bf16.h>
#include <stdint.h>

// Problem constants (B=8, S=4096 -> N rows; C = M = 2048)
#define NROWS 32768
#define KDIM  2048   // inner dim of both GEMMs
#define MDIM  2048   // output cols of both GEMMs

typedef __attribute__((ext_vector_type(8))) __bf16 bf16x8;
typedef __attribute__((ext_vector_type(4))) __bf16 bf16x4;
typedef __attribute__((ext_vector_type(4))) float  f32x4;

// ---------------------------------------------------------------------------
// async global->LDS, 16B per lane, wave-uniform LDS base + lane*16
// ---------------------------------------------------------------------------
__device__ __forceinline__ void gload16(const __bf16* g, __bf16* l) {
    __builtin_amdgcn_global_load_lds(
        (__attribute__((address_space(1))) void*)(g),
        (__attribute__((address_space(3))) void*)(l), 16, 0, 0);
}

// ---------------------------------------------------------------------------
// Weight transpose + bf16 hi/lo split:  W[K][M] fp32 -> Wt_hi/Wt_lo [M][K] bf16
// (weights stay 2-plane: near-exact to 2^-17; they are the cheap operand)
// ---------------------------------------------------------------------------
__global__ __launch_bounds__(256) void wsplit(const float* __restrict__ W,
                                              __bf16* __restrict__ th,
                                              __bf16* __restrict__ tl) {
    __shared__ float tile[32][33];
    const int bx = blockIdx.x & 63;   // m-tile
    const int by = blockIdx.x >> 6;   // k-tile
    const int tx = threadIdx.x & 31;
    const int ty = threadIdx.x >> 5;  // 0..7
#pragma unroll
    for (int i = 0; i < 32; i += 8)
        tile[ty + i][tx] = W[(size_t)(by * 32 + ty + i) * MDIM + bx * 32 + tx];
    __syncthreads();
#pragma unroll
    for (int i = 0; i < 32; i += 8) {
        const int m = bx * 32 + ty + i;
        const int k = by * 32 + tx;
        const float v = tile[tx][ty + i];
        const __bf16 hb = (__bf16)v;
        const __bf16 lb = (__bf16)(v - (float)hb);
        th[(size_t)m * KDIM + k] = hb;
        tl[(size_t)m * KDIM + k] = lb;
    }
}

// ---------------------------------------------------------------------------
// Fused LayerNorm + SiLU -> single bf16 plane. One block per row (C=2048).
// ---------------------------------------------------------------------------
__global__ __launch_bounds__(256) void ln_silu(const float* __restrict__ in,
                                               const float* __restrict__ g,
                                               const float* __restrict__ beta,
                                               __bf16* __restrict__ hi) {
    const int row  = blockIdx.x;
    const int tid  = threadIdx.x;
    const int lane = tid & 63;
    const int wv   = tid >> 6;
    const float* rp = in + (size_t)row * KDIM;

    const float4 v0 = ((const float4*)rp)[tid];         // cols 4t .. 4t+3
    const float4 v1 = ((const float4*)rp)[tid + 256];   // cols 1024+4t ..

    float s = v0.x + v0.y + v0.z + v0.w + v1.x + v1.y + v1.z + v1.w;
    float q = v0.x * v0.x + v0.y * v0.y + v0.z * v0.z + v0.w * v0.w +
              v1.x * v1.x + v1.y * v1.y + v1.z * v1.z + v1.w * v1.w;

#pragma unroll
    for (int off = 32; off > 0; off >>= 1) {
        s += __shfl_xor(s, off, 64);
        q += __shfl_xor(q, off, 64);
    }
    __shared__ float red[8];
    if (lane == 0) { red[wv] = s; red[4 + wv] = q; }
    __syncthreads();
    s = red[0] + red[1] + red[2] + red[3];
    q = red[4] + red[5] + red[6] + red[7];

    const float mu   = s * (1.0f / KDIM);
    const float var  = q * (1.0f / KDIM) - mu * mu;
    const float rstd = rsqrtf(var + 1e-6f);

    auto emit = [&](float4 v, int c0) {
        bf16x4 h4;
        const float xs[4] = {v.x, v.y, v.z, v.w};
#pragma unroll
        for (int j = 0; j < 4; j++) {
            const int c = c0 + j;
            const float t  = (xs[j] - mu) * rstd * g[c] + beta[c];
            const float sv = t / (1.0f + __expf(-t));
            h4[j] = (__bf16)sv;
        }
        *(bf16x4*)(hi + (size_t)row * KDIM + c0) = h4;
    };
    emit(v0, tid * 4);
    emit(v1, 1024 + tid * 4);
}

// ---------------------------------------------------------------------------
// 2-product GEMM:  out[N][M] = Ah[N][K] * (Bh + Bl)[M][K]^T (+bias) (+residual)
// A single bf16 plane; W exact via hi/lo planes. acc += Ah*Bh + Ah*Bl (fp32)
// 128x128 tile, BK=32, 256 threads (4 waves, each 64x64), 16x16x32 MFMA.
// ---------------------------------------------------------------------------
__global__ __launch_bounds__(256, 2) void gemm2p(
        const __bf16* __restrict__ Ah,
        const __bf16* __restrict__ Bh, const __bf16* __restrict__ Bl,
        const float* __restrict__ bias, const float* __restrict__ res,
        float* __restrict__ out) {
    __shared__ __align__(16) __bf16 sAh[128 * 32];
    __shared__ __align__(16) __bf16 sBh[128 * 32];
    __shared__ __align__(16) __bf16 sBl[128 * 32];

    const int tid  = threadIdx.x;
    const int lane = tid & 63;
    const int wv   = tid >> 6;     // 0..3
    const int wr   = wv >> 1;      // wave row (0..1)
    const int wc   = wv & 1;       // wave col (0..1)
    const int ml   = lane & 15;
    const int qk   = lane >> 4;    // 0..3

    const int bx = blockIdx.x;
    const int m0 = (bx >> 4) * 128;   // row-tile base (N/128 = 256 tiles)
    const int n0 = (bx & 15) * 128;   // col-tile base (M/128 = 16 tiles)

    // staging geometry: chunk c = wv*2+qq covers LDS elements [c*512, c*512+512)
    // lane i writes element c*512 + i*8  (hardware: wave-uniform base + lane*16B)
    const int ch   = wv * 2;
    const int srow = lane >> 2;          // 0..15
    const int skof = (lane & 3) * 8;     // 0,8,16,24

    f32x4 acc[4][4] = {};

    for (int kb = 0; kb < KDIM; kb += 32) {
#pragma unroll
        for (int qq = 0; qq < 2; qq++) {
            const int r    = (ch + qq) * 16 + srow;
            const int lofs = (ch + qq) * 512;
            const size_t ga = (size_t)(m0 + r) * KDIM + kb + skof;
            const size_t gb = (size_t)(n0 + r) * KDIM + kb + skof;
            gload16(Ah + ga, sAh + lofs);
            gload16(Bh + gb, sBh + lofs);
            gload16(Bl + gb, sBl + lofs);
        }
        __syncthreads();

        bf16x8 ah[4];
#pragma unroll
        for (int mi = 0; mi < 4; mi++) {
            const int ao = (wr * 64 + mi * 16 + ml) * 32 + qk * 8;
            ah[mi] = *(const bf16x8*)&sAh[ao];
        }
#pragma unroll
        for (int ni = 0; ni < 4; ni++) {
            const int bo = (wc * 64 + ni * 16 + ml) * 32 + qk * 8;
            const bf16x8 bh = *(const bf16x8*)&sBh[bo];
            const bf16x8 bl = *(const bf16x8*)&sBl[bo];
#pragma unroll
            for (int mi = 0; mi < 4; mi++) {
                acc[mi][ni] = __builtin_amdgcn_mfma_f32_16x16x32_bf16(ah[mi], bh, acc[mi][ni], 0, 0, 0);
                acc[mi][ni] = __builtin_amdgcn_mfma_f32_16x16x32_bf16(ah[mi], bl, acc[mi][ni], 0, 0, 0);
            }
        }
        __syncthreads();
    }

    // epilogue: C/D layout col = lane&15, row = qk*4 + reg
#pragma unroll
    for (int mi = 0; mi < 4; mi++) {
        const int gm = m0 + wr * 64 + mi * 16 + qk * 4;
#pragma unroll
        for (int ni = 0; ni < 4; ni++) {
            const int gn = n0 + wc * 64 + ni * 16 + ml;
            const float bv = bias[gn];
#pragma unroll
            for (int r = 0; r < 4; r++) {
                const size_t idx = (size_t)(gm + r) * MDIM + gn;
                float v = acc[mi][ni][r] + bv;
                if (res) v += res[idx];
                out[idx] = v;
            }
        }
    }
}

// ---------------------------------------------------------------------------
// Orchestration
//   ws layout (bytes):
//     [0,       128MB)  Ah  (activation bf16 plane, N*K)
//     [128MB,   136MB)  B1h   [136MB, 144MB) B1l
//     [144MB,   152MB)  B2h   [152MB, 160MB) B2l
//   y1 (GEMM1 output, fp32 N*M) lives in d_out until overwritten by GEMM2.
// ---------------------------------------------------------------------------
extern "C" void kernel_launch(void* const* d_in, const int* in_sizes, int n_in,
                              void* d_out, int out_size, void* d_ws, size_t ws_size,
                              hipStream_t stream) {
    const float* x   = (const float*)d_in[0];
    const float* w1  = (const float*)d_in[1];
    const float* b1  = (const float*)d_in[2];
    const float* w2  = (const float*)d_in[3];
    const float* b2  = (const float*)d_in[4];
    const float* g1  = (const float*)d_in[5];
    const float* be1 = (const float*)d_in[6];
    const float* g2  = (const float*)d_in[7];
    const float* be2 = (const float*)d_in[8];
    float* out = (float*)d_out;

    char* ws = (char*)d_ws;
    const size_t PLANE = (size_t)NROWS * KDIM * 2;   // 128 MiB
    const size_t WPL   = (size_t)KDIM * MDIM * 2;    // 8 MiB
    __bf16* Ah  = (__bf16*)(ws);
    __bf16* B1h = (__bf16*)(ws + PLANE);
    __bf16* B1l = (__bf16*)(ws + PLANE + WPL);
    __bf16* B2h = (__bf16*)(ws + PLANE + 2 * WPL);
    __bf16* B2l = (__bf16*)(ws + PLANE + 3 * WPL);

    wsplit<<<4096, 256, 0, stream>>>(w1, B1h, B1l);
    wsplit<<<4096, 256, 0, stream>>>(w2, B2h, B2l);

    ln_silu<<<NROWS, 256, 0, stream>>>(x, g1, be1, Ah);
    gemm2p<<<(NROWS / 128) * (MDIM / 128), 256, 0, stream>>>(
        Ah, B1h, B1l, b1, nullptr, out);

    ln_silu<<<NROWS, 256, 0, stream>>>(out, g2, be2, Ah);
    gemm2p<<<(NROWS / 128) * (MDIM / 128), 256, 0, stream>>>(
        Ah, B2h, B2l, b2, x, out);
}